// Round 4
// baseline (472.449 us; speedup 1.0000x reference)
//
#include <hip/hip_runtime.h>

// GRU cell, B=16384, E=H=1024. fp32 in/out, bf16 MFMA compute.
//
// R7 structure (vs R6: register-fragment double-buffer "reads-ahead" + 2
// barriers/tile instead of 8; staging ledger unchanged):
//   pre:  cast x,h -> bf16;  6 weights -> transposed bf16, Z/R stacked to N=2048
//   ZR:   [x|h](16384x2048) @ Bzr^T(2048x2048) -> ztb=bf16(sigmoid), ab=bf16(h*sigmoid)
//   H:    [x|ab](16384x2048) @ Wh^T(1024x2048) -> out = h + z*(tanh-h), fp32
// GEMM: 256x256 tile, BK=64, 512 thr / 8 waves (2Mx4N), per-wave 128x64,
// acc[8][4] f32x4. LDS 128 KiB: A,B each [2 dbuf][2 khalf][256][32] bf16.
// 4 phases/tile: pP computes (m-half, k-slice) = (0,0)(4,0)(0,1)(4,1).
// Phase body: [stage 1 half][issue ds_reads for NEXT phase into alt frag buf]
// [lgkmcnt(#just-issued) -> prev phase's frags ready, new reads stay in
// flight under MFMA][sched_barrier(0)][setprio(1) 16 MFMA setprio(0)]
// [vm4 + s_barrier only at p1/p3]. Reads-ahead map (tile kt, d=kt&1):
//   p0-body reads (d,0) m4->af1 | p1: (d,1) m0->af0 + B->bfr1
//   p2: (d,1) m4->af1          | p3: (d^1,0) m0->af0 + B->bfr0
// Staging (unchanged R6 ledger): p0 A(kt+1,1); p1 B(kt+1,1); p2 A(kt+2,0);
// p3 B(kt+2,0). vmcnt(4) at p1/p3. Slot-safety: last reads of a slot retire
// at the counted-lgkm before the p1/p3 barrier that precedes its overwrite
// (verified for (d,0),(d,1) recycling and tail tiles 30/31).
// Swizzle (unchanged): [256][32] rows, 16B chunk ^= (row>>1)&3, conflict-free
// floor; inverse on global_load_lds source, forward on ds_read col.

typedef short bf16x8 __attribute__((ext_vector_type(8)));
typedef float f32x4 __attribute__((ext_vector_type(4)));

template <int V> struct Ic { static constexpr int value = V; };

static __device__ __forceinline__ unsigned short f2bf(float f) {
    unsigned int u = __float_as_uint(f);
    return (unsigned short)((u + 0x7fffu + ((u >> 16) & 1u)) >> 16);
}
static __device__ __forceinline__ float bf2f(unsigned short s) {
    return __uint_as_float(((unsigned int)s) << 16);
}

// ---- cast x and h to bf16 in one launch ------------------------------------
__global__ void cast2_f32_bf16(const float* __restrict__ a,
                               const float* __restrict__ b,
                               unsigned short* __restrict__ da,
                               unsigned short* __restrict__ db, int n) {
    int i = (blockIdx.x * blockDim.x + threadIdx.x) * 4;
    const float* s;
    unsigned short* d;
    int off;
    if (i < n) { s = a; d = da; off = i; }
    else       { s = b; d = db; off = i - n; }
    float4 v = *(const float4*)(s + off);
    ushort4 o;
    o.x = f2bf(v.x); o.y = f2bf(v.y); o.z = f2bf(v.z); o.w = f2bf(v.w);
    *(ushort4*)(d + off) = o;
}

// ---- transpose+cast all 6 weights in one launch ----------------------------
struct TPlan {
    const float* src[6];
    unsigned short* dst[6];  // pre-offset; row stride 2048
};
__global__ void transpose_cast6(TPlan p) {
    __shared__ float t[32][33];
    const float* src = p.src[blockIdx.z];
    unsigned short* dst = p.dst[blockIdx.z];
    int bx = blockIdx.x, by = blockIdx.y;
    int tx = threadIdx.x, ty = threadIdx.y;  // 32 x 8
#pragma unroll
    for (int i = 0; i < 4; ++i)
        t[ty + 8 * i][tx] = src[(by * 32 + ty + 8 * i) * 1024 + bx * 32 + tx];
    __syncthreads();
#pragma unroll
    for (int i = 0; i < 4; ++i) {
        int n = bx * 32 + ty + 8 * i;  // dst row (N)
        int k = by * 32 + tx;          // dst col (K)
        dst[n * 2048 + k] = f2bf(t[tx][ty + 8 * i]);
    }
}

// ---- fused GEMM, 256x256, reads-ahead 4-phase schedule ----------------------
// MODE 0 (ZR): N=2048 (cols 0-1023 = z gate, 1024-2047 = r gate)
// MODE 1 (H):  N=1024
template <int MODE, int NBN_LOG>
__global__ __launch_bounds__(512, 2) void gemm_gru(
        const unsigned short* __restrict__ Alo,  // k in [0,1024), stride 1024
        const unsigned short* __restrict__ Ahi,  // k in [1024,2048), stride 1024
        const unsigned short* __restrict__ Bt,   // [N][2048]
        const float* __restrict__ bias_z,
        const float* __restrict__ bias_r,
        const unsigned short* __restrict__ hb,   // bf16 h
        const unsigned short* __restrict__ ztb_in,
        const float* __restrict__ hf,            // fp32 h
        unsigned short* __restrict__ ztb_out,
        unsigned short* __restrict__ ab_out,
        float* __restrict__ out) {
    constexpr int NBN = 1 << NBN_LOG;
    constexpr int NT = 32;  // 2048 / 64
    // [dbuf][khalf][256 rows][32 cols] bf16 = 16 KB per half-slot
    __shared__ __attribute__((aligned(16))) short As[2][2][256 * 32];
    __shared__ __attribute__((aligned(16))) short Bs[2][2][256 * 32];

    const int t = threadIdx.x;
    const int lane = t & 63;
    const int wave = t >> 6;
    const int wm = wave >> 2, wn = wave & 3;  // 2M x 4N

    // XCD swizzle: all NBN bn-blocks of one bm A-panel are stride-8 in
    // blockIdx -> same XCD L2. nwg % 8 == 0 -> bijective.
    const int i = blockIdx.x;
    const int bml = i & 7;
    const int bn = (i >> 3) & (NBN - 1);
    const int bmg = i >> (3 + NBN_LOG);
    const int bm = bmg * 8 + bml;

    const int l4 = lane & 15, kg = lane >> 4;
    // ds_read element col with swizzle: chunk kg ^ ((row>>1)&3); row-term
    // reduces to (l4>>1)&3 for all fragments (mi*16, wm*128 etc. == 0 mod 4).
    const int rdcol = ((kg ^ ((l4 >> 1) & 3)) * 8);
    const int aoff = (wm * 128 + l4) * 32 + rdcol;
    const int boff = (wn * 64 + l4) * 32 + rdcol;

    // staging: thread t, chunk j -> LDS row j*128 + (t>>2), chunk t&3.
    // inverse swizzle on global source col: chunk (t&3) ^ ((t>>3)&3).
    const int srow = t >> 2;                            // 0..127
    const int scol = (((t & 3) ^ ((t >> 3) & 3)) * 8);  // 0..24
    const int rowA0 = bm * 256;
    const int rowB0 = bn * 256;

    f32x4 acc[8][4] = {};
    bf16x8 af[2][4];   // A frags, double-buffered per phase
    bf16x8 bfr[2][4];  // B frags, double-buffered per k-slice

    // one half-tile = 256 rows x 32 cols = 16 KB = 2 loads/thread
    auto stage_half = [&](const unsigned short* src, int stride, int grow0,
                          int kcol, short* dst) {
#pragma unroll
        for (int j = 0; j < 2; ++j) {
            const unsigned short* g =
                src + (size_t)(grow0 + j * 128 + srow) * stride + (kcol + scol);
            __builtin_amdgcn_global_load_lds(
                (const __attribute__((address_space(1))) void*)g,
                (__attribute__((address_space(3))) void*)(dst + (j * 512 + wave * 64) * 8),
                16, 0, 0);
        }
    };
    auto stage_A = [&](int T, int s) {
        const unsigned short* Ab = (T < 16) ? Alo : Ahi;
        stage_half(Ab, 1024, rowA0, ((T * 64) & 1023) + s * 32, &As[T & 1][s][0]);
    };
    auto stage_B = [&](int T, int s) {
        stage_half(Bt, 2048, rowB0, T * 64 + s * 32, &Bs[T & 1][s][0]);
    };

    auto nop = [] {};
    auto vm4 = [] { asm volatile("s_waitcnt vmcnt(4)" ::: "memory"); };
    auto vm0 = [] { asm volatile("s_waitcnt vmcnt(0)" ::: "memory"); };

    // Phase: [stage][issue next-phase ds_reads][counted lgkm -> prev reads
    // done][sched_barrier][MFMA m0 with af[PA],bfr[PB]][vm][barrier?].
    // RK: 0 = no reads, 4 = A only, 8 = A + B.
    auto phase = [&](auto M0C, auto PAC, auto PBC, auto RKC, auto RDC,
                     auto RSC, auto RMC, auto RAC, auto RBC, auto stage,
                     auto vmw, auto barC) {
        constexpr int m0 = decltype(M0C)::value;
        constexpr int pa = decltype(PAC)::value;
        constexpr int pb = decltype(PBC)::value;
        constexpr int rk = decltype(RKC)::value;
        constexpr int rd = decltype(RDC)::value;
        constexpr int rs = decltype(RSC)::value;
        constexpr int rm = decltype(RMC)::value;
        constexpr int ra = decltype(RAC)::value;
        constexpr int rb = decltype(RBC)::value;
        stage();
        if constexpr (rk >= 4) {
            const short* Ab = &As[rd][rs][aoff];
            af[ra][0] = *(const bf16x8*)(Ab + (rm + 0) * 512);
            af[ra][1] = *(const bf16x8*)(Ab + (rm + 1) * 512);
            af[ra][2] = *(const bf16x8*)(Ab + (rm + 2) * 512);
            af[ra][3] = *(const bf16x8*)(Ab + (rm + 3) * 512);
        }
        if constexpr (rk == 8) {
            const short* Bb = &Bs[rd][rs][boff];
#pragma unroll
            for (int ni = 0; ni < 4; ++ni)
                bfr[rb][ni] = *(const bf16x8*)(Bb + ni * 512);
        }
        if constexpr (rk == 8)
            asm volatile("s_waitcnt lgkmcnt(8)" ::: "memory");
        else if constexpr (rk == 4)
            asm volatile("s_waitcnt lgkmcnt(4)" ::: "memory");
        else
            asm volatile("s_waitcnt lgkmcnt(0)" ::: "memory");
        __builtin_amdgcn_sched_barrier(0);
        __builtin_amdgcn_s_setprio(1);
#pragma unroll
        for (int ni = 0; ni < 4; ++ni) {
            acc[m0 + 0][ni] = __builtin_amdgcn_mfma_f32_16x16x32_bf16(
                af[pa][0], bfr[pb][ni], acc[m0 + 0][ni], 0, 0, 0);
            acc[m0 + 1][ni] = __builtin_amdgcn_mfma_f32_16x16x32_bf16(
                af[pa][1], bfr[pb][ni], acc[m0 + 1][ni], 0, 0, 0);
        }
#pragma unroll
        for (int ni = 0; ni < 4; ++ni) {
            acc[m0 + 2][ni] = __builtin_amdgcn_mfma_f32_16x16x32_bf16(
                af[pa][2], bfr[pb][ni], acc[m0 + 2][ni], 0, 0, 0);
            acc[m0 + 3][ni] = __builtin_amdgcn_mfma_f32_16x16x32_bf16(
                af[pa][3], bfr[pb][ni], acc[m0 + 3][ni], 0, 0, 0);
        }
        __builtin_amdgcn_s_setprio(0);
        vmw();
        if constexpr (decltype(barC)::value) __builtin_amdgcn_s_barrier();
    };

    // Prologue: tile0 (4 halves) + tile1 kh0 (2 halves) = 12 loads.
    stage_A(0, 0); stage_B(0, 0); stage_A(0, 1); stage_B(0, 1);
    stage_A(1, 0); stage_B(1, 0);
    asm volatile("s_waitcnt vmcnt(4)" ::: "memory");  // tile0 landed
    __builtin_amdgcn_s_barrier();
    // Pre-read tile0:p0 frags (af[0] m0=0, bfr[0] from slot (0,0)); no wait.
    {
        const short* Ab = &As[0][0][aoff];
        af[0][0] = *(const bf16x8*)(Ab + 0 * 512);
        af[0][1] = *(const bf16x8*)(Ab + 1 * 512);
        af[0][2] = *(const bf16x8*)(Ab + 2 * 512);
        af[0][3] = *(const bf16x8*)(Ab + 3 * 512);
        const short* Bb = &Bs[0][0][boff];
#pragma unroll
        for (int ni = 0; ni < 4; ++ni)
            bfr[0][ni] = *(const bf16x8*)(Bb + ni * 512);
    }

    // Generic tile kt (d = kt&1):
    //  p0: MFMA(0,af0,bfr0)  reads (d,0)m4->af1       stage A(kt+1,1)
    //  p1: MFMA(4,af1,bfr0)  reads (d,1)m0->af0,B->b1 stage B(kt+1,1) vm4 BAR
    //  p2: MFMA(0,af0,bfr1)  reads (d,1)m4->af1       stage A(kt+2,0)
    //  p3: MFMA(4,af1,bfr1)  reads (d^1,0)m0->af0,B->b0 stage B(kt+2,0) vm4 BAR
    auto tileF = [&](auto dC, int kt, bool last2) {
        constexpr int d = decltype(dC)::value;
        phase(Ic<0>{}, Ic<0>{}, Ic<0>{}, Ic<4>{}, Ic<d>{}, Ic<0>{}, Ic<4>{},
              Ic<1>{}, Ic<0>{}, [&] { stage_A(kt + 1, 1); }, nop, Ic<0>{});
        phase(Ic<4>{}, Ic<1>{}, Ic<0>{}, Ic<8>{}, Ic<d>{}, Ic<1>{}, Ic<0>{},
              Ic<0>{}, Ic<1>{}, [&] { stage_B(kt + 1, 1); }, vm4, Ic<1>{});
        if (!last2) {
            phase(Ic<0>{}, Ic<0>{}, Ic<1>{}, Ic<4>{}, Ic<d>{}, Ic<1>{}, Ic<4>{},
                  Ic<1>{}, Ic<0>{}, [&] { stage_A(kt + 2, 0); }, nop, Ic<0>{});
            phase(Ic<4>{}, Ic<1>{}, Ic<1>{}, Ic<8>{}, Ic<d ^ 1>{}, Ic<0>{},
                  Ic<0>{}, Ic<0>{}, Ic<0>{}, [&] { stage_B(kt + 2, 0); }, vm4,
                  Ic<1>{});
        } else {
            phase(Ic<0>{}, Ic<0>{}, Ic<1>{}, Ic<4>{}, Ic<d>{}, Ic<1>{}, Ic<4>{},
                  Ic<1>{}, Ic<0>{}, nop, nop, Ic<0>{});
            phase(Ic<4>{}, Ic<1>{}, Ic<1>{}, Ic<8>{}, Ic<d ^ 1>{}, Ic<0>{},
                  Ic<0>{}, Ic<0>{}, Ic<0>{}, nop, vm0, Ic<1>{});
        }
    };

    for (int kt = 0; kt < NT - 2; kt += 2) {
        tileF(Ic<0>{}, kt, false);
        tileF(Ic<1>{}, kt + 1, false);
    }
    // Tile 30 (d=0): stages A(31,1)/B(31,1) at p0/p1; drain at p3.
    tileF(Ic<0>{}, NT - 2, true);
    // Tile 31 (d=1): pure compute; no stages, no vm, no barriers.
    phase(Ic<0>{}, Ic<0>{}, Ic<0>{}, Ic<4>{}, Ic<1>{}, Ic<0>{}, Ic<4>{},
          Ic<1>{}, Ic<0>{}, nop, nop, Ic<0>{});
    phase(Ic<4>{}, Ic<1>{}, Ic<0>{}, Ic<8>{}, Ic<1>{}, Ic<1>{}, Ic<0>{},
          Ic<0>{}, Ic<1>{}, nop, nop, Ic<0>{});
    phase(Ic<0>{}, Ic<0>{}, Ic<1>{}, Ic<4>{}, Ic<1>{}, Ic<1>{}, Ic<4>{},
          Ic<1>{}, Ic<0>{}, nop, nop, Ic<0>{});
    phase(Ic<4>{}, Ic<1>{}, Ic<1>{}, Ic<0>{}, Ic<0>{}, Ic<0>{}, Ic<0>{},
          Ic<0>{}, Ic<0>{}, nop, nop, Ic<0>{});

    // Epilogue. C/D layout: col = lane&15, row = (lane>>4)*4 + reg  [m89]
    const int q4 = kg * 4;
#pragma unroll
    for (int mi = 0; mi < 8; ++mi) {
        int row0 = bm * 256 + wm * 128 + mi * 16 + q4;
#pragma unroll
        for (int ni = 0; ni < 4; ++ni) {
            int colg = bn * 256 + wn * 64 + ni * 16 + l4;
            if (MODE == 0) {
                bool isZ = colg < 1024;  // block-uniform (256 | 1024)
                int col = colg & 1023;
                float bz = isZ ? bias_z[col] : bias_r[col];
#pragma unroll
                for (int r = 0; r < 4; ++r) {
                    int idx = (row0 + r) * 1024 + col;
                    float v = acc[mi][ni][r] + bz;
                    float s = 1.0f / (1.0f + __expf(-v));
                    if (isZ) ztb_out[idx] = f2bf(s);
                    else     ab_out[idx] = f2bf(bf2f(hb[idx]) * s);
                }
            } else {
                float bz = bias_z[colg];
#pragma unroll
                for (int r = 0; r < 4; ++r) {
                    int idx = (row0 + r) * 1024 + colg;
                    float v = acc[mi][ni][r] + bz;
                    // tanh, saturation-safe: 1 - 2/(e^{2v}+1)
                    float e = __expf(2.0f * v);
                    float ht = 1.0f - 2.0f / (e + 1.0f);
                    float hv = hf[idx];
                    float z = bf2f(ztb_in[idx]);
                    out[idx] = fmaf(z, ht - hv, hv);
                }
            }
        }
    }
}

extern "C" void kernel_launch(void* const* d_in, const int* in_sizes, int n_in,
                              void* d_out, int out_size, void* d_ws, size_t ws_size,
                              hipStream_t stream) {
    const float* x    = (const float*)d_in[0];
    const float* h    = (const float*)d_in[1];
    const float* W_ri = (const float*)d_in[2];
    const float* b_ri = (const float*)d_in[3];
    const float* W_rh = (const float*)d_in[4];
    const float* W_zi = (const float*)d_in[5];
    const float* b_zi = (const float*)d_in[6];
    const float* W_zh = (const float*)d_in[7];
    const float* W_hi = (const float*)d_in[8];
    const float* b_hi = (const float*)d_in[9];
    const float* W_hh = (const float*)d_in[10];
    float* out = (float*)d_out;

    const size_t MB = 1024ull * 1024ull;
    char* ws = (char*)d_ws;
    unsigned short* xb   = (unsigned short*)(ws);             // 32 MB
    unsigned short* hb   = (unsigned short*)(ws + 32 * MB);   // 32 MB
    unsigned short* ab   = (unsigned short*)(ws + 64 * MB);   // 32 MB
    unsigned short* ztb  = (unsigned short*)(ws + 96 * MB);   // 32 MB
    unsigned short* Bzr  = (unsigned short*)(ws + 128 * MB);  // 8 MB  [2048][2048]
    unsigned short* Bh   = (unsigned short*)(ws + 136 * MB);  // 4 MB  [1024][2048]

    const int NELEM = 16384 * 1024;
    cast2_f32_bf16<<<2 * NELEM / (256 * 4), 256, 0, stream>>>(x, h, xb, hb, NELEM);

    TPlan p;
    p.src[0] = W_zi; p.dst[0] = Bzr + 0 * 2048 + 0;
    p.src[1] = W_zh; p.dst[1] = Bzr + 0 * 2048 + 1024;
    p.src[2] = W_ri; p.dst[2] = Bzr + 1024 * 2048 + 0;
    p.src[3] = W_rh; p.dst[3] = Bzr + 1024 * 2048 + 1024;
    p.src[4] = W_hi; p.dst[4] = Bh + 0;
    p.src[5] = W_hh; p.dst[5] = Bh + 1024;
    transpose_cast6<<<dim3(32, 32, 6), dim3(32, 8), 0, stream>>>(p);

    // ZR: 64 bm * 8 bn = 512 blocks; H: 64 bm * 4 bn = 256 blocks
    gemm_gru<0, 3><<<512, 512, 0, stream>>>(xb, hb, Bzr, b_zi, b_ri,
                                            hb, nullptr, nullptr,
                                            ztb, ab, nullptr);
    gemm_gru<1, 2><<<256, 512, 0, stream>>>(xb, ab, Bh, b_hi, nullptr,
                                            nullptr, ztb, h,
                                            nullptr, nullptr, out);
}